// Round 11
// baseline (3145.350 us; speedup 1.0000x reference)
//
#include <hip/hip_runtime.h>

// Round 11: d_out is FLOAT32 (proven by R10 oracle: u16 plant in fp32 low half
// was invisible). Verified pipeline, fp32 end-to-end.

#define HD 128
#define TD 64
constexpr float SLOPE = 11.0f / 48.0f;

// in-degree via integer atomics
__global__ __launch_bounds__(256)
void deg_kernel(const int* __restrict__ dst, int E, int* __restrict__ degi)
{
    int e = blockIdx.x * 256 + threadIdx.x;
    if (e < E) atomicAdd(&degi[dst[e]], 1);
}

// edge scatter: S[dst] += h[src] - rel[etype]   (32 threads/edge, float4)
__global__ __launch_bounds__(256)
void scat_kernel(const float* __restrict__ hin, const float* __restrict__ rel,
                 const int* __restrict__ src, const int* __restrict__ dst,
                 const int* __restrict__ ety, float* __restrict__ S, int E)
{
    int gid = blockIdx.x * 256 + threadIdx.x;
    int e = gid >> 5;
    if (e >= E) return;
    int lane4 = (gid & 31) * 4;
    const float4 hv = *(const float4*)&hin[(size_t)src[e] * HD + lane4];
    const float4 rv = *(const float4*)&rel[(size_t)ety[e] * HD + lane4];
    float* out = &S[(size_t)dst[e] * HD + lane4];
    atomicAdd(out + 0, hv.x - rv.x);
    atomicAdd(out + 1, hv.y - rv.y);
    atomicAdd(out + 2, hv.z - rv.z);
    atomicAdd(out + 3, hv.w - rv.w);
}

// per-node layer: block = one node, 128 threads = 128 cols (LDS-staged rows)
__global__ __launch_bounds__(128)
void node_kernel(const float* __restrict__ S, const float* __restrict__ Hin,
                 const int* __restrict__ degi,
                 const float* __restrict__ Wn, const float* __restrict__ Lw,
                 const float* __restrict__ Ew,
                 float* __restrict__ Hout, int Nn)
{
    int n = blockIdx.x;
    if (n >= Nn) return;
    int j = threadIdx.x;
    __shared__ float sS[HD], sH[HD];
    sS[j] = S[(size_t)n * HD + j];
    sH[j] = Hin[(size_t)n * HD + j];
    __syncthreads();
    int d = degi[n];
    float nrm = 1.0f / (float)((d > 0) ? d : 1);
    const float* W2 = (d > 0) ? Lw : Ew;
    float a1 = 0.f, a2 = 0.f;
    #pragma unroll 8
    for (int k = 0; k < HD; k++) {
        a1 = fmaf(sS[k], Wn[k * HD + j], a1);
        a2 = fmaf(sH[k], W2[k * HD + j], a2);
    }
    float o = a1 * nrm + a2;
    o = (o >= 0.f) ? o : o * SLOPE;
    Hout[(size_t)n * HD + j] = o;
}

// gather + time embedding -> FP32 output [R, 192]
__global__ __launch_bounds__(192)
void out_kernel(const float* __restrict__ h2, const int* __restrict__ ids,
                const int* __restrict__ tms,
                const float* __restrict__ tw, const float* __restrict__ tb,
                float* __restrict__ out, int R, int Nn)
{
    int r = blockIdx.x;
    int c = threadIdx.x;
    if (r >= R) return;
    float v;
    if (c < HD) {
        int id = ids[r];
        v = (id >= 0 && id < Nn) ? h2[(size_t)id * HD + c] : 0.0f;
    } else {
        int j = c - HD;
        v = cosf((float)tms[r] * tw[j] + tb[j]);
    }
    out[(size_t)r * (HD + TD) + c] = v;
}

extern "C" void kernel_launch(void* const* d_in, const int* in_sizes, int n_in,
                              void* d_out, int out_size, void* d_ws, size_t ws_size,
                              hipStream_t stream)
{
    const float* h   = (const float*)d_in[0];
    const float* rel = (const float*)d_in[1];
    const float* wn1 = (const float*)d_in[2];
    const float* lw1 = (const float*)d_in[3];
    const float* ew1 = (const float*)d_in[4];
    const float* wn2 = (const float*)d_in[5];
    const float* lw2 = (const float*)d_in[6];
    const float* ew2 = (const float*)d_in[7];
    const float* tw  = (const float*)d_in[8];
    const float* tb  = (const float*)d_in[9];
    const int* src = (const int*)d_in[10];
    const int* dst = (const int*)d_in[11];
    const int* ety = (const int*)d_in[12];
    const int* ids = (const int*)d_in[13];
    const int* tms = (const int*)d_in[14];

    const int Nn = in_sizes[0] / HD;
    const int E  = in_sizes[10];
    const int R  = in_sizes[13];
    const size_t matB = (size_t)Nn * HD * sizeof(float);

    char* ws = (char*)d_ws;
    const size_t degB = ((size_t)Nn * sizeof(int) + 255) & ~(size_t)255;
    int*   degi = (int*)ws;
    float* S    = (float*)(ws + degB);
    float* h1   = (float*)(ws + degB + matB);
    float* h2   = (float*)(ws + degB + 2 * matB);

    // zero deg + S every call (no cross-call state)
    hipMemsetAsync(ws, 0, degB + matB, stream);

    const int eb  = (E + 255) / 256;
    const int sb  = (int)(((size_t)E * 32 + 255) / 256);

    deg_kernel<<<eb, 256, 0, stream>>>(dst, E, degi);

    // layer 1
    scat_kernel<<<sb, 256, 0, stream>>>(h, rel, src, dst, ety, S, E);
    node_kernel<<<Nn, 128, 0, stream>>>(S, h, degi, wn1, lw1, ew1, h1, Nn);

    // layer 2
    hipMemsetAsync(S, 0, matB, stream);
    scat_kernel<<<sb, 256, 0, stream>>>(h1, rel, src, dst, ety, S, E);
    node_kernel<<<Nn, 128, 0, stream>>>(S, h1, degi, wn2, lw2, ew2, h2, Nn);

    // output (fp32)
    out_kernel<<<R, 192, 0, stream>>>(h2, ids, tms, tw, tb, (float*)d_out, R, Nn);
}

// Round 12
// 505.941 us; speedup vs baseline: 6.2168x; 6.2168x over previous
//
#include <hip/hip_runtime.h>

// Round 12: CSR-gather aggregation (no float atomics) + 8-node-tiled layer GEMM.

#define HD 128
#define TD 64
#define NPB 8            // nodes per block in node_kernel
constexpr float SLOPE = 11.0f / 48.0f;

// ---- CSR build ------------------------------------------------------------
__global__ __launch_bounds__(256)
void deg_kernel(const int* __restrict__ dst, int E, int* __restrict__ degi)
{
    int e = blockIdx.x * 256 + threadIdx.x;
    if (e < E) atomicAdd(&degi[dst[e]], 1);
}

// single-block exclusive prefix scan: degi[0..Nn) -> rowstart[0..Nn]
__global__ __launch_bounds__(256)
void scan_kernel(const int* __restrict__ degi, int* __restrict__ rowstart, int Nn)
{
    __shared__ int partial[256];
    const int t = threadIdx.x;
    const int chunk = (Nn + 255) / 256;
    const int lo = t * chunk;
    const int hi = (lo + chunk < Nn) ? lo + chunk : Nn;
    int s = 0;
    for (int i = lo; i < hi; i++) s += degi[i];
    partial[t] = s;
    __syncthreads();
    if (t == 0) {
        int acc = 0;
        for (int i = 0; i < 256; i++) { int v = partial[i]; partial[i] = acc; acc += v; }
        rowstart[Nn] = acc;   // == E
    }
    __syncthreads();
    int acc = partial[t];
    for (int i = lo; i < hi; i++) { rowstart[i] = acc; acc += degi[i]; }
}

// bucket-fill: elist[rowstart[dst]+pos] = (src, ety)
__global__ __launch_bounds__(256)
void fill_kernel(const int* __restrict__ src, const int* __restrict__ dst,
                 const int* __restrict__ ety, const int* __restrict__ rowstart,
                 int* __restrict__ cursor, int2* __restrict__ elist, int E)
{
    int e = blockIdx.x * 256 + threadIdx.x;
    if (e >= E) return;
    int d = dst[e];
    int pos = atomicAdd(&cursor[d], 1);
    elist[rowstart[d] + pos] = make_int2(src[e], ety[e]);
}

// ---- gather-aggregate: block = one dst node, 128 threads = row -------------
//   S[n,c] = sum_{e in in(n)} ( hin[src_e, c] - rel[ety_e, c] )
__global__ __launch_bounds__(128)
void gagg_kernel(const float* __restrict__ hin, const float* __restrict__ rel,
                 const int2* __restrict__ elist, const int* __restrict__ rowstart,
                 float* __restrict__ S, int Nn)
{
    int n = blockIdx.x;
    if (n >= Nn) return;
    int c = threadIdx.x;
    int beg = rowstart[n], end = rowstart[n + 1];
    float acc = 0.f;
    for (int i = beg; i < end; i++) {
        int2 se = elist[i];
        acc += hin[(size_t)se.x * HD + c] - rel[(size_t)se.y * HD + c];
    }
    S[(size_t)n * HD + c] = acc;   // full overwrite -> no memset of S needed
}

// ---- layer: NPB nodes per block, 128 threads = output cols -----------------
//   Hout[n,j] = rrelu( a1/max(deg,1) + Hin[n,:]·(deg>0?Lw:Ew)[:,j] )
// NOTE: Hout may alias S — block stages its own rows in LDS before writing.
__global__ __launch_bounds__(128)
void node_kernel(const float* S, const float* __restrict__ Hin,
                 const int* __restrict__ degi,
                 const float* __restrict__ Wn, const float* __restrict__ Lw,
                 const float* __restrict__ Ew,
                 float* Hout, int Nn)
{
    const int n0 = blockIdx.x * NPB;
    const int j  = threadIdx.x;
    __shared__ float sS[NPB][HD], sH[NPB][HD];
    #pragma unroll
    for (int m = 0; m < NPB; m++) {
        int n = n0 + m; if (n >= Nn) n = Nn - 1;
        sS[m][j] = S  [(size_t)n * HD + j];
        sH[m][j] = Hin[(size_t)n * HD + j];
    }
    __syncthreads();
    float a1[NPB] = {}, a2[NPB] = {};
    for (int k = 0; k < HD; k++) {
        float w1 = Wn[k * HD + j];
        float w2 = Lw[k * HD + j];
        #pragma unroll
        for (int m = 0; m < NPB; m++) {
            a1[m] = fmaf(sS[m][k], w1, a1[m]);
            a2[m] = fmaf(sH[m][k], w2, a2[m]);
        }
    }
    #pragma unroll
    for (int m = 0; m < NPB; m++) {
        int n = n0 + m;
        if (n >= Nn) break;
        int d = degi[n];
        float o;
        if (d > 0) {
            o = a1[m] / (float)d + a2[m];
        } else {
            // isolated node (rare): loop term uses evolve weight, norm=1
            float e2 = 0.f;
            for (int k = 0; k < HD; k++) e2 = fmaf(sH[m][k], Ew[k * HD + j], e2);
            o = a1[m] + e2;
        }
        o = (o >= 0.f) ? o : o * SLOPE;
        Hout[(size_t)n * HD + j] = o;
    }
}

// ---- gather + time embedding -> FP32 output [R, 192] -----------------------
__global__ __launch_bounds__(192)
void out_kernel(const float* __restrict__ h2, const int* __restrict__ ids,
                const int* __restrict__ tms,
                const float* __restrict__ tw, const float* __restrict__ tb,
                float* __restrict__ out, int R, int Nn)
{
    int r = blockIdx.x;
    int c = threadIdx.x;
    if (r >= R) return;
    float v;
    if (c < HD) {
        int id = ids[r];
        v = (id >= 0 && id < Nn) ? h2[(size_t)id * HD + c] : 0.0f;
    } else {
        int j = c - HD;
        v = cosf((float)tms[r] * tw[j] + tb[j]);
    }
    out[(size_t)r * (HD + TD) + c] = v;
}

extern "C" void kernel_launch(void* const* d_in, const int* in_sizes, int n_in,
                              void* d_out, int out_size, void* d_ws, size_t ws_size,
                              hipStream_t stream)
{
    const float* h   = (const float*)d_in[0];
    const float* rel = (const float*)d_in[1];
    const float* wn1 = (const float*)d_in[2];
    const float* lw1 = (const float*)d_in[3];
    const float* ew1 = (const float*)d_in[4];
    const float* wn2 = (const float*)d_in[5];
    const float* lw2 = (const float*)d_in[6];
    const float* ew2 = (const float*)d_in[7];
    const float* tw  = (const float*)d_in[8];
    const float* tb  = (const float*)d_in[9];
    const int* src = (const int*)d_in[10];
    const int* dst = (const int*)d_in[11];
    const int* ety = (const int*)d_in[12];
    const int* ids = (const int*)d_in[13];
    const int* tms = (const int*)d_in[14];

    const int Nn = in_sizes[0] / HD;
    const int E  = in_sizes[10];
    const int R  = in_sizes[13];
    const size_t matB = (size_t)Nn * HD * sizeof(float);

    // workspace layout (~58.6 MB; h2 aliases S)
    char* ws = (char*)d_ws;
    const size_t iN = ((size_t)Nn * sizeof(int) + 255) & ~(size_t)255;
    int*  degi     = (int*)(ws);
    int*  cursor   = (int*)(ws + iN);
    int*  rowstart = (int*)(ws + 2 * iN);                 // Nn+1 ints
    int2* elist    = (int2*)(ws + 3 * iN + 256);
    float* S       = (float*)(ws + 3 * iN + 256 + (size_t)E * sizeof(int2));
    float* h1      = (float*)((char*)S + matB);
    float* h2      = S;   // alias: node_kernel/out_kernel safe per-row staging

    // zero deg + cursor (contiguous)
    hipMemsetAsync(ws, 0, 2 * iN, stream);

    const int eb = (E + 255) / 256;

    // CSR build
    deg_kernel<<<eb, 256, 0, stream>>>(dst, E, degi);
    scan_kernel<<<1, 256, 0, stream>>>(degi, rowstart, Nn);
    fill_kernel<<<eb, 256, 0, stream>>>(src, dst, ety, rowstart, cursor, elist, E);

    const int nb = (Nn + NPB - 1) / NPB;

    // layer 1
    gagg_kernel<<<Nn, 128, 0, stream>>>(h, rel, elist, rowstart, S, Nn);
    node_kernel<<<nb, 128, 0, stream>>>(S, h, degi, wn1, lw1, ew1, h1, Nn);

    // layer 2 (gagg overwrites S fully; node_kernel writes h2=S, safe)
    gagg_kernel<<<Nn, 128, 0, stream>>>(h1, rel, elist, rowstart, S, Nn);
    node_kernel<<<nb, 128, 0, stream>>>(S, h1, degi, wn2, lw2, ew2, h2, Nn);

    // output (fp32)
    out_kernel<<<R, 192, 0, stream>>>(h2, ids, tms, tw, tb, (float*)d_out, R, Nn);
}

// Round 13
// 410.203 us; speedup vs baseline: 7.6678x; 1.2334x over previous
//
#include <hip/hip_runtime.h>

// Round 13: ILP-4 gather-aggregate + register-tiled layer GEMM (64x128 tile).

#define HD 128
#define TD 64
constexpr float SLOPE = 11.0f / 48.0f;

// ---- CSR build ------------------------------------------------------------
__global__ __launch_bounds__(256)
void deg_kernel(const int* __restrict__ dst, int E, int* __restrict__ degi)
{
    int e = blockIdx.x * 256 + threadIdx.x;
    if (e < E) atomicAdd(&degi[dst[e]], 1);
}

// single-block exclusive prefix scan: degi[0..Nn) -> rowstart[0..Nn]
__global__ __launch_bounds__(1024)
void scan_kernel(const int* __restrict__ degi, int* __restrict__ rowstart, int Nn)
{
    __shared__ int partial[1024];
    const int t = threadIdx.x;
    const int chunk = (Nn + 1023) / 1024;
    const int lo = t * chunk;
    const int hi = (lo + chunk < Nn) ? lo + chunk : Nn;
    int s = 0;
    for (int i = lo; i < hi; i++) s += degi[i];
    partial[t] = s;
    __syncthreads();
    if (t == 0) {
        int acc = 0;
        for (int i = 0; i < 1024; i++) { int v = partial[i]; partial[i] = acc; acc += v; }
        rowstart[Nn] = acc;   // == E
    }
    __syncthreads();
    int acc = partial[t];
    for (int i = lo; i < hi; i++) { rowstart[i] = acc; acc += degi[i]; }
}

// bucket-fill: elist[rowstart[dst]+pos] = (src, ety)
__global__ __launch_bounds__(256)
void fill_kernel(const int* __restrict__ src, const int* __restrict__ dst,
                 const int* __restrict__ ety, const int* __restrict__ rowstart,
                 int* __restrict__ cursor, int2* __restrict__ elist, int E)
{
    int e = blockIdx.x * 256 + threadIdx.x;
    if (e >= E) return;
    int d = dst[e];
    int pos = atomicAdd(&cursor[d], 1);
    elist[rowstart[d] + pos] = make_int2(src[e], ety[e]);
}

// ---- gather-aggregate, ILP-4: block = one dst node, 128 threads = row ------
__global__ __launch_bounds__(128)
void gagg_kernel(const float* __restrict__ hin, const float* __restrict__ rel,
                 const int2* __restrict__ elist, const int* __restrict__ rowstart,
                 float* __restrict__ S, int Nn)
{
    int n = blockIdx.x;
    if (n >= Nn) return;
    int c = threadIdx.x;
    int beg = rowstart[n], end = rowstart[n + 1];
    float a0 = 0.f, a1 = 0.f, a2 = 0.f, a3 = 0.f;
    int i = beg;
    for (; i + 4 <= end; i += 4) {
        int2 e0 = elist[i], e1 = elist[i + 1], e2 = elist[i + 2], e3 = elist[i + 3];
        float h0 = hin[(size_t)e0.x * HD + c], r0 = rel[(size_t)e0.y * HD + c];
        float h1 = hin[(size_t)e1.x * HD + c], r1 = rel[(size_t)e1.y * HD + c];
        float h2 = hin[(size_t)e2.x * HD + c], r2 = rel[(size_t)e2.y * HD + c];
        float h3 = hin[(size_t)e3.x * HD + c], r3 = rel[(size_t)e3.y * HD + c];
        a0 += h0 - r0; a1 += h1 - r1; a2 += h2 - r2; a3 += h3 - r3;
    }
    for (; i < end; i++) {
        int2 e = elist[i];
        a0 += hin[(size_t)e.x * HD + c] - rel[(size_t)e.y * HD + c];
    }
    S[(size_t)n * HD + c] = (a0 + a1) + (a2 + a3);   // full overwrite
}

// ---- layer GEMM: 64 nodes x 128 cols per block, 256 threads ----------------
//  thread (tx=tid&31, ty=tid>>5): 8 rows (ty+8r) x 4 cols (tx*4..+3)
//  Hout[n,:] = rrelu( (S[n,:]@Wn)/max(deg,1) + Hin[n,:]@(deg>0?Lw:Ew) )
//  Hout may alias S: block writes only rows it alone reads, after all reads.
__global__ __launch_bounds__(256)
void gemm_kernel(const float* Sm, const float* __restrict__ Hin,
                 const int* __restrict__ degi,
                 const float* __restrict__ Wn, const float* __restrict__ Lw,
                 const float* __restrict__ Ew,
                 float* Hout, int Nn)
{
    __shared__ float As[64][32];
    __shared__ float Ws[32][HD];
    const int tid = threadIdx.x;
    const int tx = tid & 31, ty = tid >> 5;
    const int tx4 = tx * 4;
    const int row0 = blockIdx.x * 64;
    float acc1[8][4] = {};   // S @ Wn
    float acc2[8][4] = {};   // Hin @ Lw

#define GEMM_PASS(Aptr, Wptr, ACC)                                              \
    for (int kc = 0; kc < HD; kc += 32) {                                       \
        __syncthreads();                                                        \
        {                                                                       \
            int r = tid >> 3, kk = (tid & 7) * 4;                               \
            int ra = row0 + r;      if (ra >= Nn) ra = Nn - 1;                  \
            int rb = row0 + r + 32; if (rb >= Nn) rb = Nn - 1;                  \
            *(float4*)&As[r][kk]      = *(const float4*)&Aptr[(size_t)ra * HD + kc + kk]; \
            *(float4*)&As[r + 32][kk] = *(const float4*)&Aptr[(size_t)rb * HD + kc + kk]; \
            _Pragma("unroll")                                                   \
            for (int i = 0; i < 4; i++) {                                       \
                int f = i * 256 + tid;                                          \
                int k = f >> 5, col = (f & 31) * 4;                             \
                *(float4*)&Ws[k][col] =                                         \
                    *(const float4*)&Wptr[(size_t)(kc + k) * HD + col];         \
            }                                                                   \
        }                                                                       \
        __syncthreads();                                                        \
        for (int k0 = 0; k0 < 32; k0 += 4) {                                    \
            float as[8][4];                                                     \
            _Pragma("unroll")                                                   \
            for (int r = 0; r < 8; r++)                                         \
                *(float4*)as[r] = *(const float4*)&As[ty + 8 * r][k0];          \
            _Pragma("unroll")                                                   \
            for (int kk = 0; kk < 4; kk++) {                                    \
                const float4 wv = *(const float4*)&Ws[k0 + kk][tx4];            \
                _Pragma("unroll")                                               \
                for (int r = 0; r < 8; r++) {                                   \
                    ACC[r][0] = fmaf(as[r][kk], wv.x, ACC[r][0]);               \
                    ACC[r][1] = fmaf(as[r][kk], wv.y, ACC[r][1]);               \
                    ACC[r][2] = fmaf(as[r][kk], wv.z, ACC[r][2]);               \
                    ACC[r][3] = fmaf(as[r][kk], wv.w, ACC[r][3]);               \
                }                                                               \
            }                                                                   \
        }                                                                       \
    }

    GEMM_PASS(Sm, Wn, acc1)
    GEMM_PASS(Hin, Lw, acc2)
#undef GEMM_PASS

    #pragma unroll
    for (int r = 0; r < 8; r++) {
        int row = row0 + ty + 8 * r;
        if (row >= Nn) continue;
        int d = degi[row];
        float o0, o1, o2, o3;
        if (d > 0) {
            float nrm = 1.0f / (float)d;
            o0 = fmaf(acc1[r][0], nrm, acc2[r][0]);
            o1 = fmaf(acc1[r][1], nrm, acc2[r][1]);
            o2 = fmaf(acc1[r][2], nrm, acc2[r][2]);
            o3 = fmaf(acc1[r][3], nrm, acc2[r][3]);
        } else {
            // isolated node (rare): loop term uses evolve weight, norm = 1
            float e0 = 0.f, e1 = 0.f, e2 = 0.f, e3 = 0.f;
            for (int k = 0; k < HD; k++) {
                float a = Hin[(size_t)row * HD + k];
                const float4 w = *(const float4*)&Ew[(size_t)k * HD + tx4];
                e0 = fmaf(a, w.x, e0); e1 = fmaf(a, w.y, e1);
                e2 = fmaf(a, w.z, e2); e3 = fmaf(a, w.w, e3);
            }
            o0 = acc1[r][0] + e0; o1 = acc1[r][1] + e1;
            o2 = acc1[r][2] + e2; o3 = acc1[r][3] + e3;
        }
        o0 = (o0 >= 0.f) ? o0 : o0 * SLOPE;
        o1 = (o1 >= 0.f) ? o1 : o1 * SLOPE;
        o2 = (o2 >= 0.f) ? o2 : o2 * SLOPE;
        o3 = (o3 >= 0.f) ? o3 : o3 * SLOPE;
        *(float4*)&Hout[(size_t)row * HD + tx4] = make_float4(o0, o1, o2, o3);
    }
}

// ---- gather + time embedding -> FP32 output [R, 192] -----------------------
__global__ __launch_bounds__(192)
void out_kernel(const float* __restrict__ h2, const int* __restrict__ ids,
                const int* __restrict__ tms,
                const float* __restrict__ tw, const float* __restrict__ tb,
                float* __restrict__ out, int R, int Nn)
{
    int r = blockIdx.x;
    int c = threadIdx.x;
    if (r >= R) return;
    float v;
    if (c < HD) {
        int id = ids[r];
        v = (id >= 0 && id < Nn) ? h2[(size_t)id * HD + c] : 0.0f;
    } else {
        int j = c - HD;
        v = cosf((float)tms[r] * tw[j] + tb[j]);
    }
    out[(size_t)r * (HD + TD) + c] = v;
}

extern "C" void kernel_launch(void* const* d_in, const int* in_sizes, int n_in,
                              void* d_out, int out_size, void* d_ws, size_t ws_size,
                              hipStream_t stream)
{
    const float* h   = (const float*)d_in[0];
    const float* rel = (const float*)d_in[1];
    const float* wn1 = (const float*)d_in[2];
    const float* lw1 = (const float*)d_in[3];
    const float* ew1 = (const float*)d_in[4];
    const float* wn2 = (const float*)d_in[5];
    const float* lw2 = (const float*)d_in[6];
    const float* ew2 = (const float*)d_in[7];
    const float* tw  = (const float*)d_in[8];
    const float* tb  = (const float*)d_in[9];
    const int* src = (const int*)d_in[10];
    const int* dst = (const int*)d_in[11];
    const int* ety = (const int*)d_in[12];
    const int* ids = (const int*)d_in[13];
    const int* tms = (const int*)d_in[14];

    const int Nn = in_sizes[0] / HD;
    const int E  = in_sizes[10];
    const int R  = in_sizes[13];
    const size_t matB = (size_t)Nn * HD * sizeof(float);

    // workspace (~58.6 MB): degi | cursor | rowstart | elist | S | h1 ; h2=S
    char* ws = (char*)d_ws;
    const size_t iN = ((size_t)Nn * sizeof(int) + 255) & ~(size_t)255;
    int*  degi     = (int*)(ws);
    int*  cursor   = (int*)(ws + iN);
    int*  rowstart = (int*)(ws + 2 * iN);                 // Nn+1 ints
    int2* elist    = (int2*)(ws + 3 * iN + 256);
    float* S       = (float*)(ws + 3 * iN + 256 + (size_t)E * sizeof(int2));
    float* h1      = (float*)((char*)S + matB);
    float* h2      = S;   // alias (safe: per-block row ownership, writes last)

    hipMemsetAsync(ws, 0, 2 * iN, stream);   // degi + cursor

    const int eb = (E + 255) / 256;
    const int gb = (Nn + 63) / 64;

    // CSR build (reused by both layers)
    deg_kernel<<<eb, 256, 0, stream>>>(dst, E, degi);
    scan_kernel<<<1, 1024, 0, stream>>>(degi, rowstart, Nn);
    fill_kernel<<<eb, 256, 0, stream>>>(src, dst, ety, rowstart, cursor, elist, E);

    // layer 1
    gagg_kernel<<<Nn, 128, 0, stream>>>(h, rel, elist, rowstart, S, Nn);
    gemm_kernel<<<gb, 256, 0, stream>>>(S, h, degi, wn1, lw1, ew1, h1, Nn);

    // layer 2
    gagg_kernel<<<Nn, 128, 0, stream>>>(h1, rel, elist, rowstart, S, Nn);
    gemm_kernel<<<gb, 256, 0, stream>>>(S, h1, degi, wn2, lw2, ew2, h2, Nn);

    // output (fp32)
    out_kernel<<<R, 192, 0, stream>>>(h2, ids, tms, tw, tb, (float*)d_out, R, Nn);
}

// Round 14
// 351.900 us; speedup vs baseline: 8.9382x; 1.1657x over previous
//
#include <hip/hip_runtime.h>

// Round 14: hierarchical 3-kernel prefix scan replaces the 83-us single-block scan.

#define HD 128
#define TD 64
constexpr float SLOPE = 11.0f / 48.0f;

// ---- CSR build ------------------------------------------------------------
__global__ __launch_bounds__(256)
void deg_kernel(const int* __restrict__ dst, int E, int* __restrict__ degi)
{
    int e = blockIdx.x * 256 + threadIdx.x;
    if (e < E) atomicAdd(&degi[dst[e]], 1);
}

// scan stage 1: blocksum[b] = sum of degi[b*1024 .. b*1024+1023)
__global__ __launch_bounds__(256)
void scan1_kernel(const int* __restrict__ degi, int* __restrict__ blocksum, int Nn)
{
    __shared__ int red[256];
    const int b = blockIdx.x, t = threadIdx.x;
    int s = 0;
    #pragma unroll
    for (int j = 0; j < 4; j++) {
        int i = b * 1024 + j * 256 + t;
        if (i < Nn) s += degi[i];
    }
    red[t] = s;
    __syncthreads();
    for (int off = 128; off; off >>= 1) {
        if (t < off) red[t] += red[t + off];
        __syncthreads();
    }
    if (t == 0) blocksum[b] = red[0];
}

// scan stage 2: serial exclusive scan of NB (~49) block sums; writes total to rowstartN
__global__ __launch_bounds__(64)
void scan2_kernel(int* __restrict__ blocksum, int NB, int* __restrict__ rowstartN)
{
    if (threadIdx.x == 0 && blockIdx.x == 0) {
        int acc = 0;
        for (int b = 0; b < NB; b++) { int v = blocksum[b]; blocksum[b] = acc; acc += v; }
        *rowstartN = acc;   // rowstart[Nn] == E
    }
}

// scan stage 3: per-block exclusive scan (Hillis-Steele) + block offset
__global__ __launch_bounds__(1024)
void scan3_kernel(const int* __restrict__ degi, const int* __restrict__ blocksum,
                  int* __restrict__ rowstart, int Nn)
{
    __shared__ int buf[1024];
    const int b = blockIdx.x, t = threadIdx.x;
    const int i = b * 1024 + t;
    const int v = (i < Nn) ? degi[i] : 0;
    buf[t] = v;
    __syncthreads();
    for (int off = 1; off < 1024; off <<= 1) {
        int x = (t >= off) ? buf[t - off] : 0;
        __syncthreads();
        buf[t] += x;
        __syncthreads();
    }
    if (i < Nn) rowstart[i] = blocksum[b] + buf[t] - v;   // exclusive
}

// bucket-fill: elist[rowstart[dst]+pos] = (src, ety)
__global__ __launch_bounds__(256)
void fill_kernel(const int* __restrict__ src, const int* __restrict__ dst,
                 const int* __restrict__ ety, const int* __restrict__ rowstart,
                 int* __restrict__ cursor, int2* __restrict__ elist, int E)
{
    int e = blockIdx.x * 256 + threadIdx.x;
    if (e >= E) return;
    int d = dst[e];
    int pos = atomicAdd(&cursor[d], 1);
    elist[rowstart[d] + pos] = make_int2(src[e], ety[e]);
}

// ---- gather-aggregate, ILP-4: block = one dst node, 128 threads = row ------
__global__ __launch_bounds__(128)
void gagg_kernel(const float* __restrict__ hin, const float* __restrict__ rel,
                 const int2* __restrict__ elist, const int* __restrict__ rowstart,
                 float* __restrict__ S, int Nn)
{
    int n = blockIdx.x;
    if (n >= Nn) return;
    int c = threadIdx.x;
    int beg = rowstart[n], end = rowstart[n + 1];
    float a0 = 0.f, a1 = 0.f, a2 = 0.f, a3 = 0.f;
    int i = beg;
    for (; i + 4 <= end; i += 4) {
        int2 e0 = elist[i], e1 = elist[i + 1], e2 = elist[i + 2], e3 = elist[i + 3];
        float h0 = hin[(size_t)e0.x * HD + c], r0 = rel[(size_t)e0.y * HD + c];
        float h1 = hin[(size_t)e1.x * HD + c], r1 = rel[(size_t)e1.y * HD + c];
        float h2 = hin[(size_t)e2.x * HD + c], r2 = rel[(size_t)e2.y * HD + c];
        float h3 = hin[(size_t)e3.x * HD + c], r3 = rel[(size_t)e3.y * HD + c];
        a0 += h0 - r0; a1 += h1 - r1; a2 += h2 - r2; a3 += h3 - r3;
    }
    for (; i < end; i++) {
        int2 e = elist[i];
        a0 += hin[(size_t)e.x * HD + c] - rel[(size_t)e.y * HD + c];
    }
    S[(size_t)n * HD + c] = (a0 + a1) + (a2 + a3);   // full overwrite
}

// ---- layer GEMM: 64 nodes x 128 cols per block, 256 threads ----------------
__global__ __launch_bounds__(256)
void gemm_kernel(const float* Sm, const float* __restrict__ Hin,
                 const int* __restrict__ degi,
                 const float* __restrict__ Wn, const float* __restrict__ Lw,
                 const float* __restrict__ Ew,
                 float* Hout, int Nn)
{
    __shared__ float As[64][32];
    __shared__ float Ws[32][HD];
    const int tid = threadIdx.x;
    const int tx = tid & 31, ty = tid >> 5;
    const int tx4 = tx * 4;
    const int row0 = blockIdx.x * 64;
    float acc1[8][4] = {};   // S @ Wn
    float acc2[8][4] = {};   // Hin @ Lw

#define GEMM_PASS(Aptr, Wptr, ACC)                                              \
    for (int kc = 0; kc < HD; kc += 32) {                                       \
        __syncthreads();                                                        \
        {                                                                       \
            int r = tid >> 3, kk = (tid & 7) * 4;                               \
            int ra = row0 + r;      if (ra >= Nn) ra = Nn - 1;                  \
            int rb = row0 + r + 32; if (rb >= Nn) rb = Nn - 1;                  \
            *(float4*)&As[r][kk]      = *(const float4*)&Aptr[(size_t)ra * HD + kc + kk]; \
            *(float4*)&As[r + 32][kk] = *(const float4*)&Aptr[(size_t)rb * HD + kc + kk]; \
            _Pragma("unroll")                                                   \
            for (int i = 0; i < 4; i++) {                                       \
                int f = i * 256 + tid;                                          \
                int k = f >> 5, col = (f & 31) * 4;                             \
                *(float4*)&Ws[k][col] =                                         \
                    *(const float4*)&Wptr[(size_t)(kc + k) * HD + col];         \
            }                                                                   \
        }                                                                       \
        __syncthreads();                                                        \
        for (int k0 = 0; k0 < 32; k0 += 4) {                                    \
            float as[8][4];                                                     \
            _Pragma("unroll")                                                   \
            for (int r = 0; r < 8; r++)                                         \
                *(float4*)as[r] = *(const float4*)&As[ty + 8 * r][k0];          \
            _Pragma("unroll")                                                   \
            for (int kk = 0; kk < 4; kk++) {                                    \
                const float4 wv = *(const float4*)&Ws[k0 + kk][tx4];            \
                _Pragma("unroll")                                               \
                for (int r = 0; r < 8; r++) {                                   \
                    ACC[r][0] = fmaf(as[r][kk], wv.x, ACC[r][0]);               \
                    ACC[r][1] = fmaf(as[r][kk], wv.y, ACC[r][1]);               \
                    ACC[r][2] = fmaf(as[r][kk], wv.z, ACC[r][2]);               \
                    ACC[r][3] = fmaf(as[r][kk], wv.w, ACC[r][3]);               \
                }                                                               \
            }                                                                   \
        }                                                                       \
    }

    GEMM_PASS(Sm, Wn, acc1)
    GEMM_PASS(Hin, Lw, acc2)
#undef GEMM_PASS

    #pragma unroll
    for (int r = 0; r < 8; r++) {
        int row = row0 + ty + 8 * r;
        if (row >= Nn) continue;
        int d = degi[row];
        float o0, o1, o2, o3;
        if (d > 0) {
            float nrm = 1.0f / (float)d;
            o0 = fmaf(acc1[r][0], nrm, acc2[r][0]);
            o1 = fmaf(acc1[r][1], nrm, acc2[r][1]);
            o2 = fmaf(acc1[r][2], nrm, acc2[r][2]);
            o3 = fmaf(acc1[r][3], nrm, acc2[r][3]);
        } else {
            float e0 = 0.f, e1 = 0.f, e2 = 0.f, e3 = 0.f;
            for (int k = 0; k < HD; k++) {
                float a = Hin[(size_t)row * HD + k];
                const float4 w = *(const float4*)&Ew[(size_t)k * HD + tx4];
                e0 = fmaf(a, w.x, e0); e1 = fmaf(a, w.y, e1);
                e2 = fmaf(a, w.z, e2); e3 = fmaf(a, w.w, e3);
            }
            o0 = acc1[r][0] + e0; o1 = acc1[r][1] + e1;
            o2 = acc1[r][2] + e2; o3 = acc1[r][3] + e3;
        }
        o0 = (o0 >= 0.f) ? o0 : o0 * SLOPE;
        o1 = (o1 >= 0.f) ? o1 : o1 * SLOPE;
        o2 = (o2 >= 0.f) ? o2 : o2 * SLOPE;
        o3 = (o3 >= 0.f) ? o3 : o3 * SLOPE;
        *(float4*)&Hout[(size_t)row * HD + tx4] = make_float4(o0, o1, o2, o3);
    }
}

// ---- gather + time embedding -> FP32 output [R, 192] -----------------------
__global__ __launch_bounds__(192)
void out_kernel(const float* __restrict__ h2, const int* __restrict__ ids,
                const int* __restrict__ tms,
                const float* __restrict__ tw, const float* __restrict__ tb,
                float* __restrict__ out, int R, int Nn)
{
    int r = blockIdx.x;
    int c = threadIdx.x;
    if (r >= R) return;
    float v;
    if (c < HD) {
        int id = ids[r];
        v = (id >= 0 && id < Nn) ? h2[(size_t)id * HD + c] : 0.0f;
    } else {
        int j = c - HD;
        v = cosf((float)tms[r] * tw[j] + tb[j]);
    }
    out[(size_t)r * (HD + TD) + c] = v;
}

extern "C" void kernel_launch(void* const* d_in, const int* in_sizes, int n_in,
                              void* d_out, int out_size, void* d_ws, size_t ws_size,
                              hipStream_t stream)
{
    const float* h   = (const float*)d_in[0];
    const float* rel = (const float*)d_in[1];
    const float* wn1 = (const float*)d_in[2];
    const float* lw1 = (const float*)d_in[3];
    const float* ew1 = (const float*)d_in[4];
    const float* wn2 = (const float*)d_in[5];
    const float* lw2 = (const float*)d_in[6];
    const float* ew2 = (const float*)d_in[7];
    const float* tw  = (const float*)d_in[8];
    const float* tb  = (const float*)d_in[9];
    const int* src = (const int*)d_in[10];
    const int* dst = (const int*)d_in[11];
    const int* ety = (const int*)d_in[12];
    const int* ids = (const int*)d_in[13];
    const int* tms = (const int*)d_in[14];

    const int Nn = in_sizes[0] / HD;
    const int E  = in_sizes[10];
    const int R  = in_sizes[13];
    const size_t matB = (size_t)Nn * HD * sizeof(float);
    const int NB = (Nn + 1023) / 1024;   // scan blocks

    // workspace: degi | cursor | blocksum | rowstart | elist | S | h1 ; h2=S
    char* ws = (char*)d_ws;
    const size_t iN = ((size_t)Nn * sizeof(int) + 255) & ~(size_t)255;
    const size_t bN = ((size_t)NB * sizeof(int) + 255) & ~(size_t)255;
    int*  degi     = (int*)(ws);
    int*  cursor   = (int*)(ws + iN);
    int*  blocksum = (int*)(ws + 2 * iN);
    int*  rowstart = (int*)(ws + 2 * iN + bN);            // Nn+1 ints
    int2* elist    = (int2*)(ws + 2 * iN + bN + iN + 256);
    float* S       = (float*)((char*)elist + (size_t)E * sizeof(int2));
    float* h1      = (float*)((char*)S + matB);
    float* h2      = S;   // alias (safe: per-block row ownership, writes last)

    hipMemsetAsync(ws, 0, 2 * iN, stream);   // degi + cursor

    const int eb = (E + 255) / 256;
    const int gb = (Nn + 63) / 64;

    // CSR build (hierarchical scan)
    deg_kernel<<<eb, 256, 0, stream>>>(dst, E, degi);
    scan1_kernel<<<NB, 256, 0, stream>>>(degi, blocksum, Nn);
    scan2_kernel<<<1, 64, 0, stream>>>(blocksum, NB, &rowstart[Nn]);
    scan3_kernel<<<NB, 1024, 0, stream>>>(degi, blocksum, rowstart, Nn);
    fill_kernel<<<eb, 256, 0, stream>>>(src, dst, ety, rowstart, cursor, elist, E);

    // layer 1
    gagg_kernel<<<Nn, 128, 0, stream>>>(h, rel, elist, rowstart, S, Nn);
    gemm_kernel<<<gb, 256, 0, stream>>>(S, h, degi, wn1, lw1, ew1, h1, Nn);

    // layer 2
    gagg_kernel<<<Nn, 128, 0, stream>>>(h1, rel, elist, rowstart, S, Nn);
    gemm_kernel<<<gb, 256, 0, stream>>>(S, h1, degi, wn2, lw2, ew2, h2, Nn);

    // output (fp32)
    out_kernel<<<R, 192, 0, stream>>>(h2, ids, tms, tw, tb, (float*)d_out, R, Nn);
}

// Round 15
// 334.090 us; speedup vs baseline: 9.4147x; 1.0533x over previous
//
#include <hip/hip_runtime.h>

// Round 15: gemm 128x128 tile w/ 8x8 per-thread (16 FMA per ds_read_b128);
//           gagg ILP-8.

#define HD 128
#define TD 64
constexpr float SLOPE = 11.0f / 48.0f;

// ---- CSR build ------------------------------------------------------------
__global__ __launch_bounds__(256)
void deg_kernel(const int* __restrict__ dst, int E, int* __restrict__ degi)
{
    int e = blockIdx.x * 256 + threadIdx.x;
    if (e < E) atomicAdd(&degi[dst[e]], 1);
}

__global__ __launch_bounds__(256)
void scan1_kernel(const int* __restrict__ degi, int* __restrict__ blocksum, int Nn)
{
    __shared__ int red[256];
    const int b = blockIdx.x, t = threadIdx.x;
    int s = 0;
    #pragma unroll
    for (int j = 0; j < 4; j++) {
        int i = b * 1024 + j * 256 + t;
        if (i < Nn) s += degi[i];
    }
    red[t] = s;
    __syncthreads();
    for (int off = 128; off; off >>= 1) {
        if (t < off) red[t] += red[t + off];
        __syncthreads();
    }
    if (t == 0) blocksum[b] = red[0];
}

__global__ __launch_bounds__(64)
void scan2_kernel(int* __restrict__ blocksum, int NB, int* __restrict__ rowstartN)
{
    if (threadIdx.x == 0 && blockIdx.x == 0) {
        int acc = 0;
        for (int b = 0; b < NB; b++) { int v = blocksum[b]; blocksum[b] = acc; acc += v; }
        *rowstartN = acc;
    }
}

__global__ __launch_bounds__(1024)
void scan3_kernel(const int* __restrict__ degi, const int* __restrict__ blocksum,
                  int* __restrict__ rowstart, int Nn)
{
    __shared__ int buf[1024];
    const int b = blockIdx.x, t = threadIdx.x;
    const int i = b * 1024 + t;
    const int v = (i < Nn) ? degi[i] : 0;
    buf[t] = v;
    __syncthreads();
    for (int off = 1; off < 1024; off <<= 1) {
        int x = (t >= off) ? buf[t - off] : 0;
        __syncthreads();
        buf[t] += x;
        __syncthreads();
    }
    if (i < Nn) rowstart[i] = blocksum[b] + buf[t] - v;
}

__global__ __launch_bounds__(256)
void fill_kernel(const int* __restrict__ src, const int* __restrict__ dst,
                 const int* __restrict__ ety, const int* __restrict__ rowstart,
                 int* __restrict__ cursor, int2* __restrict__ elist, int E)
{
    int e = blockIdx.x * 256 + threadIdx.x;
    if (e >= E) return;
    int d = dst[e];
    int pos = atomicAdd(&cursor[d], 1);
    elist[rowstart[d] + pos] = make_int2(src[e], ety[e]);
}

// ---- gather-aggregate, ILP-8 ----------------------------------------------
__global__ __launch_bounds__(128)
void gagg_kernel(const float* __restrict__ hin, const float* __restrict__ rel,
                 const int2* __restrict__ elist, const int* __restrict__ rowstart,
                 float* __restrict__ S, int Nn)
{
    int n = blockIdx.x;
    if (n >= Nn) return;
    int c = threadIdx.x;
    int beg = rowstart[n], end = rowstart[n + 1];
    float a0 = 0.f, a1 = 0.f, a2 = 0.f, a3 = 0.f;
    float a4 = 0.f, a5 = 0.f, a6 = 0.f, a7 = 0.f;
    int i = beg;
    for (; i + 8 <= end; i += 8) {
        int2 e0 = elist[i],     e1 = elist[i + 1], e2 = elist[i + 2], e3 = elist[i + 3];
        int2 e4 = elist[i + 4], e5 = elist[i + 5], e6 = elist[i + 6], e7 = elist[i + 7];
        float h0 = hin[(size_t)e0.x * HD + c], r0 = rel[(size_t)e0.y * HD + c];
        float h1 = hin[(size_t)e1.x * HD + c], r1 = rel[(size_t)e1.y * HD + c];
        float h2 = hin[(size_t)e2.x * HD + c], r2 = rel[(size_t)e2.y * HD + c];
        float h3 = hin[(size_t)e3.x * HD + c], r3 = rel[(size_t)e3.y * HD + c];
        float h4 = hin[(size_t)e4.x * HD + c], r4 = rel[(size_t)e4.y * HD + c];
        float h5 = hin[(size_t)e5.x * HD + c], r5 = rel[(size_t)e5.y * HD + c];
        float h6 = hin[(size_t)e6.x * HD + c], r6 = rel[(size_t)e6.y * HD + c];
        float h7 = hin[(size_t)e7.x * HD + c], r7 = rel[(size_t)e7.y * HD + c];
        a0 += h0 - r0; a1 += h1 - r1; a2 += h2 - r2; a3 += h3 - r3;
        a4 += h4 - r4; a5 += h5 - r5; a6 += h6 - r6; a7 += h7 - r7;
    }
    for (; i + 4 <= end; i += 4) {
        int2 e0 = elist[i], e1 = elist[i + 1], e2 = elist[i + 2], e3 = elist[i + 3];
        a0 += hin[(size_t)e0.x * HD + c] - rel[(size_t)e0.y * HD + c];
        a1 += hin[(size_t)e1.x * HD + c] - rel[(size_t)e1.y * HD + c];
        a2 += hin[(size_t)e2.x * HD + c] - rel[(size_t)e2.y * HD + c];
        a3 += hin[(size_t)e3.x * HD + c] - rel[(size_t)e3.y * HD + c];
    }
    for (; i < end; i++) {
        int2 e = elist[i];
        a0 += hin[(size_t)e.x * HD + c] - rel[(size_t)e.y * HD + c];
    }
    S[(size_t)n * HD + c] = ((a0 + a1) + (a2 + a3)) + ((a4 + a5) + (a6 + a7));
}

// ---- layer GEMM: 128 nodes x 128 cols per block, 256 threads, 8x8/thread ---
//  thread (tx=tid&15, ty=tid>>4): rows ty+16r (r<8), cols tx*4..+3 and 64+tx*4..+3
__global__ __launch_bounds__(256, 2)
void gemm_kernel(const float* Sm, const float* __restrict__ Hin,
                 const int* __restrict__ degi,
                 const float* __restrict__ Wn, const float* __restrict__ Lw,
                 const float* __restrict__ Ew,
                 float* Hout, int Nn)
{
    __shared__ float As[128][36];   // pad 32->36: row stride 144B shifts banks by 4
    __shared__ float Ws[32][HD];
    const int tid = threadIdx.x;
    const int tx = tid & 15, ty = tid >> 4;
    const int c0 = tx * 4, c1 = 64 + tx * 4;
    const int row0 = blockIdx.x * 128;
    float acc1[8][8] = {};   // S @ Wn   [r][0..3]=c0 block, [4..7]=c1 block
    float acc2[8][8] = {};   // Hin @ Lw

#define GEMM_PASS(Aptr, Wptr, ACC)                                              \
    for (int kc = 0; kc < HD; kc += 32) {                                       \
        __syncthreads();                                                        \
        _Pragma("unroll")                                                       \
        for (int i = 0; i < 4; i++) {                                           \
            int f = i * 256 + tid;                                              \
            int r = f >> 3, kk = (f & 7) * 4;                                   \
            int gr = row0 + r; if (gr >= Nn) gr = Nn - 1;                       \
            *(float4*)&As[r][kk] = *(const float4*)&Aptr[(size_t)gr * HD + kc + kk]; \
        }                                                                       \
        _Pragma("unroll")                                                       \
        for (int i = 0; i < 4; i++) {                                           \
            int f = i * 256 + tid;                                              \
            int k = f >> 5, col = (f & 31) * 4;                                 \
            *(float4*)&Ws[k][col] = *(const float4*)&Wptr[(size_t)(kc + k) * HD + col]; \
        }                                                                       \
        __syncthreads();                                                        \
        for (int k0 = 0; k0 < 32; k0 += 4) {                                    \
            float a[8][4];                                                      \
            _Pragma("unroll")                                                   \
            for (int r = 0; r < 8; r++)                                         \
                *(float4*)a[r] = *(const float4*)&As[ty + 16 * r][k0];          \
            _Pragma("unroll")                                                   \
            for (int kk = 0; kk < 4; kk++) {                                    \
                const float4 w0 = *(const float4*)&Ws[k0 + kk][c0];             \
                const float4 w1 = *(const float4*)&Ws[k0 + kk][c1];             \
                _Pragma("unroll")                                               \
                for (int r = 0; r < 8; r++) {                                   \
                    float av = a[r][kk];                                        \
                    ACC[r][0] = fmaf(av, w0.x, ACC[r][0]);                      \
                    ACC[r][1] = fmaf(av, w0.y, ACC[r][1]);                      \
                    ACC[r][2] = fmaf(av, w0.z, ACC[r][2]);                      \
                    ACC[r][3] = fmaf(av, w0.w, ACC[r][3]);                      \
                    ACC[r][4] = fmaf(av, w1.x, ACC[r][4]);                      \
                    ACC[r][5] = fmaf(av, w1.y, ACC[r][5]);                      \
                    ACC[r][6] = fmaf(av, w1.z, ACC[r][6]);                      \
                    ACC[r][7] = fmaf(av, w1.w, ACC[r][7]);                      \
                }                                                               \
            }                                                                   \
        }                                                                       \
    }

    GEMM_PASS(Sm, Wn, acc1)
    GEMM_PASS(Hin, Lw, acc2)
#undef GEMM_PASS

    #pragma unroll
    for (int r = 0; r < 8; r++) {
        int row = row0 + ty + 16 * r;
        if (row >= Nn) continue;
        int d = degi[row];
        float o[8];
        if (d > 0) {
            float nrm = 1.0f / (float)d;
            #pragma unroll
            for (int q = 0; q < 8; q++) o[q] = fmaf(acc1[r][q], nrm, acc2[r][q]);
        } else {
            // isolated node (rare): loop term uses evolve weight, norm = 1
            float e[8] = {};
            for (int k = 0; k < HD; k++) {
                float a = Hin[(size_t)row * HD + k];
                const float4 w0 = *(const float4*)&Ew[(size_t)k * HD + c0];
                const float4 w1 = *(const float4*)&Ew[(size_t)k * HD + c1];
                e[0] = fmaf(a, w0.x, e[0]); e[1] = fmaf(a, w0.y, e[1]);
                e[2] = fmaf(a, w0.z, e[2]); e[3] = fmaf(a, w0.w, e[3]);
                e[4] = fmaf(a, w1.x, e[4]); e[5] = fmaf(a, w1.y, e[5]);
                e[6] = fmaf(a, w1.z, e[6]); e[7] = fmaf(a, w1.w, e[7]);
            }
            #pragma unroll
            for (int q = 0; q < 8; q++) o[q] = acc1[r][q] + e[q];
        }
        #pragma unroll
        for (int q = 0; q < 8; q++) o[q] = (o[q] >= 0.f) ? o[q] : o[q] * SLOPE;
        *(float4*)&Hout[(size_t)row * HD + c0] = make_float4(o[0], o[1], o[2], o[3]);
        *(float4*)&Hout[(size_t)row * HD + c1] = make_float4(o[4], o[5], o[6], o[7]);
    }
}

// ---- gather + time embedding -> FP32 output [R, 192] -----------------------
__global__ __launch_bounds__(192)
void out_kernel(const float* __restrict__ h2, const int* __restrict__ ids,
                const int* __restrict__ tms,
                const float* __restrict__ tw, const float* __restrict__ tb,
                float* __restrict__ out, int R, int Nn)
{
    int r = blockIdx.x;
    int c = threadIdx.x;
    if (r >= R) return;
    float v;
    if (c < HD) {
        int id = ids[r];
        v = (id >= 0 && id < Nn) ? h2[(size_t)id * HD + c] : 0.0f;
    } else {
        int j = c - HD;
        v = cosf((float)tms[r] * tw[j] + tb[j]);
    }
    out[(size_t)r * (HD + TD) + c] = v;
}

extern "C" void kernel_launch(void* const* d_in, const int* in_sizes, int n_in,
                              void* d_out, int out_size, void* d_ws, size_t ws_size,
                              hipStream_t stream)
{
    const float* h   = (const float*)d_in[0];
    const float* rel = (const float*)d_in[1];
    const float* wn1 = (const float*)d_in[2];
    const float* lw1 = (const float*)d_in[3];
    const float* ew1 = (const float*)d_in[4];
    const float* wn2 = (const float*)d_in[5];
    const float* lw2 = (const float*)d_in[6];
    const float* ew2 = (const float*)d_in[7];
    const float* tw  = (const float*)d_in[8];
    const float* tb  = (const float*)d_in[9];
    const int* src = (const int*)d_in[10];
    const int* dst = (const int*)d_in[11];
    const int* ety = (const int*)d_in[12];
    const int* ids = (const int*)d_in[13];
    const int* tms = (const int*)d_in[14];

    const int Nn = in_sizes[0] / HD;
    const int E  = in_sizes[10];
    const int R  = in_sizes[13];
    const size_t matB = (size_t)Nn * HD * sizeof(float);
    const int NB = (Nn + 1023) / 1024;

    // workspace: degi | cursor | blocksum | rowstart | elist | S | h1 ; h2=S
    char* ws = (char*)d_ws;
    const size_t iN = ((size_t)Nn * sizeof(int) + 255) & ~(size_t)255;
    const size_t bN = ((size_t)NB * sizeof(int) + 255) & ~(size_t)255;
    int*  degi     = (int*)(ws);
    int*  cursor   = (int*)(ws + iN);
    int*  blocksum = (int*)(ws + 2 * iN);
    int*  rowstart = (int*)(ws + 2 * iN + bN);
    int2* elist    = (int2*)(ws + 2 * iN + bN + iN + 256);
    float* S       = (float*)((char*)elist + (size_t)E * sizeof(int2));
    float* h1      = (float*)((char*)S + matB);
    float* h2      = S;   // alias (per-block row ownership; reads precede writes)

    hipMemsetAsync(ws, 0, 2 * iN, stream);   // degi + cursor

    const int eb = (E + 255) / 256;
    const int gb = (Nn + 127) / 128;

    // CSR build
    deg_kernel<<<eb, 256, 0, stream>>>(dst, E, degi);
    scan1_kernel<<<NB, 256, 0, stream>>>(degi, blocksum, Nn);
    scan2_kernel<<<1, 64, 0, stream>>>(blocksum, NB, &rowstart[Nn]);
    scan3_kernel<<<NB, 1024, 0, stream>>>(degi, blocksum, rowstart, Nn);
    fill_kernel<<<eb, 256, 0, stream>>>(src, dst, ety, rowstart, cursor, elist, E);

    // layer 1
    gagg_kernel<<<Nn, 128, 0, stream>>>(h, rel, elist, rowstart, S, Nn);
    gemm_kernel<<<gb, 256, 0, stream>>>(S, h, degi, wn1, lw1, ew1, h1, Nn);

    // layer 2
    gagg_kernel<<<Nn, 128, 0, stream>>>(h1, rel, elist, rowstart, S, Nn);
    gemm_kernel<<<gb, 256, 0, stream>>>(S, h1, degi, wn2, lw2, ew2, h2, Nn);

    // output (fp32)
    out_kernel<<<R, 192, 0, stream>>>(h2, ids, tms, tw, tb, (float*)d_out, R, Nn);
}

// Round 16
// 254.422 us; speedup vs baseline: 12.3628x; 1.3131x over previous
//
#include <hip/hip_runtime.h>

// Round 16: bf16 MFMA single-GEMM per layer (K=256 concat, S pre-scaled by 1/deg
// in gagg); bf16 h gather in gagg (halves gather bytes). No LDS/barriers in GEMM.

#define HD 128
#define TD 64
constexpr float SLOPE = 11.0f / 48.0f;

typedef unsigned short u16;
typedef unsigned int u32;
typedef short bf16x8 __attribute__((ext_vector_type(8)));
typedef float f32x4 __attribute__((ext_vector_type(4)));

__device__ __forceinline__ float bf2f(u16 b) {
    return __uint_as_float(((u32)b) << 16);
}
__device__ __forceinline__ u16 f2bf(float f) {
    u32 u = __float_as_uint(f);
    u += 0x7FFFu + ((u >> 16) & 1u);  // RNE
    return (u16)(u >> 16);
}

// ---- CSR build ------------------------------------------------------------
__global__ __launch_bounds__(256)
void deg_kernel(const int* __restrict__ dst, int E, int* __restrict__ degi)
{
    int e = blockIdx.x * 256 + threadIdx.x;
    if (e < E) atomicAdd(&degi[dst[e]], 1);
}

__global__ __launch_bounds__(256)
void scan1_kernel(const int* __restrict__ degi, int* __restrict__ blocksum, int Nn)
{
    __shared__ int red[256];
    const int b = blockIdx.x, t = threadIdx.x;
    int s = 0;
    #pragma unroll
    for (int j = 0; j < 4; j++) {
        int i = b * 1024 + j * 256 + t;
        if (i < Nn) s += degi[i];
    }
    red[t] = s;
    __syncthreads();
    for (int off = 128; off; off >>= 1) {
        if (t < off) red[t] += red[t + off];
        __syncthreads();
    }
    if (t == 0) blocksum[b] = red[0];
}

__global__ __launch_bounds__(64)
void scan2_kernel(int* __restrict__ blocksum, int NB, int* __restrict__ rowstartN)
{
    if (threadIdx.x == 0 && blockIdx.x == 0) {
        int acc = 0;
        for (int b = 0; b < NB; b++) { int v = blocksum[b]; blocksum[b] = acc; acc += v; }
        *rowstartN = acc;
    }
}

__global__ __launch_bounds__(1024)
void scan3_kernel(const int* __restrict__ degi, const int* __restrict__ blocksum,
                  int* __restrict__ rowstart, int Nn)
{
    __shared__ int buf[1024];
    const int b = blockIdx.x, t = threadIdx.x;
    const int i = b * 1024 + t;
    const int v = (i < Nn) ? degi[i] : 0;
    buf[t] = v;
    __syncthreads();
    for (int off = 1; off < 1024; off <<= 1) {
        int x = (t >= off) ? buf[t - off] : 0;
        __syncthreads();
        buf[t] += x;
        __syncthreads();
    }
    if (i < Nn) rowstart[i] = blocksum[b] + buf[t] - v;
}

__global__ __launch_bounds__(256)
void fill_kernel(const int* __restrict__ src, const int* __restrict__ dst,
                 const int* __restrict__ ety, const int* __restrict__ rowstart,
                 int* __restrict__ cursor, int2* __restrict__ elist, int E)
{
    int e = blockIdx.x * 256 + threadIdx.x;
    if (e >= E) return;
    int d = dst[e];
    int pos = atomicAdd(&cursor[d], 1);
    elist[rowstart[d] + pos] = make_int2(src[e], ety[e]);
}

// ---- fp32 -> bf16 convert -------------------------------------------------
__global__ __launch_bounds__(256)
void conv_kernel(const float4* __restrict__ in, ushort4* __restrict__ out, int n4)
{
    int i = blockIdx.x * 256 + threadIdx.x;
    if (i >= n4) return;
    float4 v = in[i];
    ushort4 o;
    o.x = f2bf(v.x); o.y = f2bf(v.y); o.z = f2bf(v.z); o.w = f2bf(v.w);
    out[i] = o;
}

// ---- build BT[col][k] bf16, k<128 from Wn, k>=128 from Lw ------------------
__global__ __launch_bounds__(256)
void bt_kernel(const float* __restrict__ Wn, const float* __restrict__ Lw,
               u16* __restrict__ BT)
{
    int idx = blockIdx.x * 256 + threadIdx.x;   // 128*256 = 32768
    int c = idx >> 8, k = idx & 255;
    float v = (k < HD) ? Wn[k * HD + c] : Lw[(k - HD) * HD + c];
    BT[(size_t)c * 256 + k] = f2bf(v);
}

// ---- gather-aggregate (bf16 h), pre-scaled by 1/max(deg,1) -----------------
// block = one dst node, 64 threads; thread c owns cols 2c, 2c+1 (u32 = 2 bf16)
__global__ __launch_bounds__(64)
void gagg_kernel(const u32* __restrict__ hbf2, const float2* __restrict__ rel2,
                 const int2* __restrict__ elist, const int* __restrict__ rowstart,
                 u32* __restrict__ Sn2, int Nn)
{
    int n = blockIdx.x;
    if (n >= Nn) return;
    int c = threadIdx.x;
    int beg = rowstart[n], end = rowstart[n + 1];
    float ae[8] = {}, ao[8] = {};
    int i = beg;
    for (; i + 8 <= end; i += 8) {
        #pragma unroll
        for (int j = 0; j < 8; j++) {
            int2 e = elist[i + j];
            u32 hv = hbf2[(size_t)e.x * 64 + c];
            float2 rv = rel2[(size_t)e.y * 64 + c];
            ae[j] += bf2f((u16)(hv & 0xffffu)) - rv.x;
            ao[j] += bf2f((u16)(hv >> 16)) - rv.y;
        }
    }
    for (; i < end; i++) {
        int2 e = elist[i];
        u32 hv = hbf2[(size_t)e.x * 64 + c];
        float2 rv = rel2[(size_t)e.y * 64 + c];
        ae[0] += bf2f((u16)(hv & 0xffffu)) - rv.x;
        ao[0] += bf2f((u16)(hv >> 16)) - rv.y;
    }
    float se = ((ae[0] + ae[1]) + (ae[2] + ae[3])) + ((ae[4] + ae[5]) + (ae[6] + ae[7]));
    float so = ((ao[0] + ao[1]) + (ao[2] + ao[3])) + ((ao[4] + ao[5]) + (ao[6] + ao[7]));
    int d = end - beg;
    float nrm = 1.0f / (float)((d > 0) ? d : 1);
    se *= nrm; so *= nrm;
    Sn2[(size_t)n * 64 + c] = (u32)f2bf(se) | ((u32)f2bf(so) << 16);
}

// ---- MFMA GEMM: out = rrelu([Sn | Hn](bf16, K=256) @ BT^T) -----------------
// block: 128 rows x 128 cols, 4 waves (wave w: rows w*32..w*32+31), no LDS.
// A-frag: lane l -> row (l&15), k (l>>4)*8..+7.  B-frag: col (l&15), same k.
// D-frag: col (l&15), row (l>>4)*4 + r.
template<int STORE_BF16>
__global__ __launch_bounds__(256)
void mfma_kernel(const u16* __restrict__ Sn, const u16* __restrict__ Hn,
                 const u16* __restrict__ BT, const int* __restrict__ degi,
                 const float* __restrict__ Ew, void* __restrict__ Out, int Nn)
{
    const int lane = threadIdx.x & 63;
    const int wave = threadIdx.x >> 6;
    const int row0 = blockIdx.x * 128 + wave * 32;
    const int lr = lane & 15;
    const int lk = (lane >> 4) * 8;

    f32x4 acc[2][8];
    #pragma unroll
    for (int m = 0; m < 2; m++)
        #pragma unroll
        for (int n = 0; n < 8; n++)
            acc[m][n] = (f32x4){0.f, 0.f, 0.f, 0.f};

    int r0 = row0 + lr;      if (r0 >= Nn) r0 = Nn - 1;
    int r1 = row0 + 16 + lr; if (r1 >= Nn) r1 = Nn - 1;
    const size_t rb0 = (size_t)r0 * HD, rb1 = (size_t)r1 * HD;

    #pragma unroll
    for (int ks = 0; ks < 8; ks++) {
        const u16* A = (ks < 4) ? Sn : Hn;
        const int kc = (ks & 3) * 32 + lk;
        bf16x8 a0 = *(const bf16x8*)&A[rb0 + kc];
        bf16x8 a1 = *(const bf16x8*)&A[rb1 + kc];
        #pragma unroll
        for (int nf = 0; nf < 8; nf++) {
            bf16x8 b = *(const bf16x8*)&BT[(size_t)(nf * 16 + lr) * 256 + ks * 32 + lk];
            acc[0][nf] = __builtin_amdgcn_mfma_f32_16x16x32_bf16(a0, b, acc[0][nf], 0, 0, 0);
            acc[1][nf] = __builtin_amdgcn_mfma_f32_16x16x32_bf16(a1, b, acc[1][nf], 0, 0, 0);
        }
    }

    #pragma unroll
    for (int mf = 0; mf < 2; mf++) {
        #pragma unroll
        for (int r = 0; r < 4; r++) {
            const int row = row0 + mf * 16 + (lane >> 4) * 4 + r;
            if (row >= Nn) continue;
            const int d = degi[row];
            #pragma unroll
            for (int nf = 0; nf < 8; nf++) {
                const int col = nf * 16 + lr;
                float o = acc[mf][nf][r];
                if (d == 0) {
                    // isolated node (rare): Sn row is 0; loop term must use Ew
                    o = 0.f;
                    for (int k = 0; k < HD; k++)
                        o = fmaf(bf2f(Hn[(size_t)row * HD + k]), Ew[(size_t)k * HD + col], o);
                }
                o = (o >= 0.f) ? o : o * SLOPE;
                if (STORE_BF16) ((u16*)Out)[(size_t)row * HD + col] = f2bf(o);
                else            ((float*)Out)[(size_t)row * HD + col] = o;
            }
        }
    }
}

// ---- gather + time embedding -> FP32 output [R, 192] -----------------------
__global__ __launch_bounds__(192)
void out_kernel(const float* __restrict__ h2, const int* __restrict__ ids,
                const int* __restrict__ tms,
                const float* __restrict__ tw, const float* __restrict__ tb,
                float* __restrict__ out, int R, int Nn)
{
    int r = blockIdx.x;
    int c = threadIdx.x;
    if (r >= R) return;
    float v;
    if (c < HD) {
        int id = ids[r];
        v = (id >= 0 && id < Nn) ? h2[(size_t)id * HD + c] : 0.0f;
    } else {
        int j = c - HD;
        v = cosf((float)tms[r] * tw[j] + tb[j]);
    }
    out[(size_t)r * (HD + TD) + c] = v;
}

extern "C" void kernel_launch(void* const* d_in, const int* in_sizes, int n_in,
                              void* d_out, int out_size, void* d_ws, size_t ws_size,
                              hipStream_t stream)
{
    const float* h   = (const float*)d_in[0];
    const float* rel = (const float*)d_in[1];
    const float* wn1 = (const float*)d_in[2];
    const float* lw1 = (const float*)d_in[3];
    const float* ew1 = (const float*)d_in[4];
    const float* wn2 = (const float*)d_in[5];
    const float* lw2 = (const float*)d_in[6];
    const float* ew2 = (const float*)d_in[7];
    const float* tw  = (const float*)d_in[8];
    const float* tb  = (const float*)d_in[9];
    const int* src = (const int*)d_in[10];
    const int* dst = (const int*)d_in[11];
    const int* ety = (const int*)d_in[12];
    const int* ids = (const int*)d_in[13];
    const int* tms = (const int*)d_in[14];

    const int Nn = in_sizes[0] / HD;
    const int E  = in_sizes[10];
    const int R  = in_sizes[13];
    const int NB = (Nn + 1023) / 1024;
    const size_t bfB = (size_t)Nn * HD * sizeof(u16);     // 12.8 MB

    // ws: degi | cursor | blocksum | rowstart | elist | hbf | h1bf | Sn | h2 | BT1 | BT2
    char* ws = (char*)d_ws;
    const size_t iN = ((size_t)Nn * sizeof(int) + 255) & ~(size_t)255;
    const size_t bN = ((size_t)NB * sizeof(int) + 255) & ~(size_t)255;
    int*  degi     = (int*)(ws);
    int*  cursor   = (int*)(ws + iN);
    int*  blocksum = (int*)(ws + 2 * iN);
    int*  rowstart = (int*)(ws + 2 * iN + bN);
    char* p        = ws + 2 * iN + bN + iN + 256;
    int2* elist    = (int2*)p;               p += (size_t)E * sizeof(int2);
    u16*  hbf      = (u16*)p;                p += bfB;
    u16*  h1bf     = (u16*)p;                p += bfB;
    u16*  Sn       = (u16*)p;                p += bfB;
    float* h2      = (float*)p;              p += (size_t)Nn * HD * sizeof(float);
    u16*  BT1      = (u16*)p;                p += HD * 256 * sizeof(u16);
    u16*  BT2      = (u16*)p;

    hipMemsetAsync(ws, 0, 2 * iN, stream);   // degi + cursor

    const int eb = (E + 255) / 256;
    const int gb = (Nn + 127) / 128;
    const int n4 = Nn * HD / 4;

    // CSR build
    deg_kernel<<<eb, 256, 0, stream>>>(dst, E, degi);
    scan1_kernel<<<NB, 256, 0, stream>>>(degi, blocksum, Nn);
    scan2_kernel<<<1, 64, 0, stream>>>(blocksum, NB, &rowstart[Nn]);
    scan3_kernel<<<NB, 1024, 0, stream>>>(degi, blocksum, rowstart, Nn);
    fill_kernel<<<eb, 256, 0, stream>>>(src, dst, ety, rowstart, cursor, elist, E);

    // conversions
    conv_kernel<<<(n4 + 255) / 256, 256, 0, stream>>>((const float4*)h, (ushort4*)hbf, n4);
    bt_kernel<<<128, 256, 0, stream>>>(wn1, lw1, BT1);
    bt_kernel<<<128, 256, 0, stream>>>(wn2, lw2, BT2);

    // layer 1: h(bf16) -> h1(bf16)
    gagg_kernel<<<Nn, 64, 0, stream>>>((const u32*)hbf, (const float2*)rel,
                                       elist, rowstart, (u32*)Sn, Nn);
    mfma_kernel<1><<<gb, 256, 0, stream>>>(Sn, hbf, BT1, degi, ew1, h1bf, Nn);

    // layer 2: h1(bf16) -> h2(fp32)
    gagg_kernel<<<Nn, 64, 0, stream>>>((const u32*)h1bf, (const float2*)rel,
                                       elist, rowstart, (u32*)Sn, Nn);
    mfma_kernel<0><<<gb, 256, 0, stream>>>(Sn, h1bf, BT2, degi, ew2, h2, Nn);

    // output (fp32)
    out_kernel<<<R, 192, 0, stream>>>(h2, ids, tms, tw, tb, (float*)d_out, R, Nn);
}

// Round 17
// 232.513 us; speedup vs baseline: 13.5276x; 1.0942x over previous
//
#include <hip/hip_runtime.h>

// Round 17: u32-packed edge list ((ety<<16)|src, halves fill's scattered-write
// amplification); rel converted to bf16 for the gather.

#define HD 128
#define TD 64
constexpr float SLOPE = 11.0f / 48.0f;

typedef unsigned short u16;
typedef unsigned int u32;
typedef short bf16x8 __attribute__((ext_vector_type(8)));
typedef float f32x4 __attribute__((ext_vector_type(4)));

__device__ __forceinline__ float bf2f(u16 b) {
    return __uint_as_float(((u32)b) << 16);
}
__device__ __forceinline__ u16 f2bf(float f) {
    u32 u = __float_as_uint(f);
    u += 0x7FFFu + ((u >> 16) & 1u);  // RNE
    return (u16)(u >> 16);
}

// ---- CSR build ------------------------------------------------------------
__global__ __launch_bounds__(256)
void deg_kernel(const int* __restrict__ dst, int E, int* __restrict__ degi)
{
    int e = blockIdx.x * 256 + threadIdx.x;
    if (e < E) atomicAdd(&degi[dst[e]], 1);
}

__global__ __launch_bounds__(256)
void scan1_kernel(const int* __restrict__ degi, int* __restrict__ blocksum, int Nn)
{
    __shared__ int red[256];
    const int b = blockIdx.x, t = threadIdx.x;
    int s = 0;
    #pragma unroll
    for (int j = 0; j < 4; j++) {
        int i = b * 1024 + j * 256 + t;
        if (i < Nn) s += degi[i];
    }
    red[t] = s;
    __syncthreads();
    for (int off = 128; off; off >>= 1) {
        if (t < off) red[t] += red[t + off];
        __syncthreads();
    }
    if (t == 0) blocksum[b] = red[0];
}

__global__ __launch_bounds__(64)
void scan2_kernel(int* __restrict__ blocksum, int NB, int* __restrict__ rowstartN)
{
    if (threadIdx.x == 0 && blockIdx.x == 0) {
        int acc = 0;
        for (int b = 0; b < NB; b++) { int v = blocksum[b]; blocksum[b] = acc; acc += v; }
        *rowstartN = acc;
    }
}

__global__ __launch_bounds__(1024)
void scan3_kernel(const int* __restrict__ degi, const int* __restrict__ blocksum,
                  int* __restrict__ rowstart, int Nn)
{
    __shared__ int buf[1024];
    const int b = blockIdx.x, t = threadIdx.x;
    const int i = b * 1024 + t;
    const int v = (i < Nn) ? degi[i] : 0;
    buf[t] = v;
    __syncthreads();
    for (int off = 1; off < 1024; off <<= 1) {
        int x = (t >= off) ? buf[t - off] : 0;
        __syncthreads();
        buf[t] += x;
        __syncthreads();
    }
    if (i < Nn) rowstart[i] = blocksum[b] + buf[t] - v;
}

// bucket-fill: elist[rowstart[dst]+pos] = (ety<<16) | src   (u32, halves bytes)
__global__ __launch_bounds__(256)
void fill_kernel(const int* __restrict__ src, const int* __restrict__ dst,
                 const int* __restrict__ ety, const int* __restrict__ rowstart,
                 int* __restrict__ cursor, u32* __restrict__ elist, int E)
{
    int e = blockIdx.x * 256 + threadIdx.x;
    if (e >= E) return;
    int d = dst[e];
    int pos = atomicAdd(&cursor[d], 1);
    elist[rowstart[d] + pos] = ((u32)ety[e] << 16) | (u32)src[e];
}

// ---- fp32 -> bf16 convert -------------------------------------------------
__global__ __launch_bounds__(256)
void conv_kernel(const float4* __restrict__ in, ushort4* __restrict__ out, int n4)
{
    int i = blockIdx.x * 256 + threadIdx.x;
    if (i >= n4) return;
    float4 v = in[i];
    ushort4 o;
    o.x = f2bf(v.x); o.y = f2bf(v.y); o.z = f2bf(v.z); o.w = f2bf(v.w);
    out[i] = o;
}

// ---- build BT[col][k] bf16, k<128 from Wn, k>=128 from Lw ------------------
__global__ __launch_bounds__(256)
void bt_kernel(const float* __restrict__ Wn, const float* __restrict__ Lw,
               u16* __restrict__ BT)
{
    int idx = blockIdx.x * 256 + threadIdx.x;   // 128*256 = 32768
    int c = idx >> 8, k = idx & 255;
    float v = (k < HD) ? Wn[k * HD + c] : Lw[(k - HD) * HD + c];
    BT[(size_t)c * 256 + k] = f2bf(v);
}

// ---- gather-aggregate (bf16 h + bf16 rel), pre-scaled by 1/max(deg,1) ------
// block = one dst node, 64 threads; thread c owns cols 2c, 2c+1 (u32 = 2 bf16)
__global__ __launch_bounds__(64)
void gagg_kernel(const u32* __restrict__ hbf2, const u32* __restrict__ relbf2,
                 const u32* __restrict__ elist, const int* __restrict__ rowstart,
                 u32* __restrict__ Sn2, int Nn)
{
    int n = blockIdx.x;
    if (n >= Nn) return;
    int c = threadIdx.x;
    int beg = rowstart[n], end = rowstart[n + 1];
    float ae[8] = {}, ao[8] = {};
    int i = beg;
    for (; i + 8 <= end; i += 8) {
        #pragma unroll
        for (int j = 0; j < 8; j++) {
            u32 v = elist[i + j];
            u32 hv = hbf2[(size_t)(v & 0xffffu) * 64 + c];
            u32 rv = relbf2[(size_t)(v >> 16) * 64 + c];
            ae[j] += bf2f((u16)(hv & 0xffffu)) - bf2f((u16)(rv & 0xffffu));
            ao[j] += bf2f((u16)(hv >> 16)) - bf2f((u16)(rv >> 16));
        }
    }
    for (; i < end; i++) {
        u32 v = elist[i];
        u32 hv = hbf2[(size_t)(v & 0xffffu) * 64 + c];
        u32 rv = relbf2[(size_t)(v >> 16) * 64 + c];
        ae[0] += bf2f((u16)(hv & 0xffffu)) - bf2f((u16)(rv & 0xffffu));
        ao[0] += bf2f((u16)(hv >> 16)) - bf2f((u16)(rv >> 16));
    }
    float se = ((ae[0] + ae[1]) + (ae[2] + ae[3])) + ((ae[4] + ae[5]) + (ae[6] + ae[7]));
    float so = ((ao[0] + ao[1]) + (ao[2] + ao[3])) + ((ao[4] + ao[5]) + (ao[6] + ao[7]));
    int d = end - beg;
    float nrm = 1.0f / (float)((d > 0) ? d : 1);
    se *= nrm; so *= nrm;
    Sn2[(size_t)n * 64 + c] = (u32)f2bf(se) | ((u32)f2bf(so) << 16);
}

// ---- MFMA GEMM: out = rrelu([Sn | Hn](bf16, K=256) @ BT^T) -----------------
template<int STORE_BF16>
__global__ __launch_bounds__(256)
void mfma_kernel(const u16* __restrict__ Sn, const u16* __restrict__ Hn,
                 const u16* __restrict__ BT, const int* __restrict__ degi,
                 const float* __restrict__ Ew, void* __restrict__ Out, int Nn)
{
    const int lane = threadIdx.x & 63;
    const int wave = threadIdx.x >> 6;
    const int row0 = blockIdx.x * 128 + wave * 32;
    const int lr = lane & 15;
    const int lk = (lane >> 4) * 8;

    f32x4 acc[2][8];
    #pragma unroll
    for (int m = 0; m < 2; m++)
        #pragma unroll
        for (int n = 0; n < 8; n++)
            acc[m][n] = (f32x4){0.f, 0.f, 0.f, 0.f};

    int r0 = row0 + lr;      if (r0 >= Nn) r0 = Nn - 1;
    int r1 = row0 + 16 + lr; if (r1 >= Nn) r1 = Nn - 1;
    const size_t rb0 = (size_t)r0 * HD, rb1 = (size_t)r1 * HD;

    #pragma unroll
    for (int ks = 0; ks < 8; ks++) {
        const u16* A = (ks < 4) ? Sn : Hn;
        const int kc = (ks & 3) * 32 + lk;
        bf16x8 a0 = *(const bf16x8*)&A[rb0 + kc];
        bf16x8 a1 = *(const bf16x8*)&A[rb1 + kc];
        #pragma unroll
        for (int nf = 0; nf < 8; nf++) {
            bf16x8 b = *(const bf16x8*)&BT[(size_t)(nf * 16 + lr) * 256 + ks * 32 + lk];
            acc[0][nf] = __builtin_amdgcn_mfma_f32_16x16x32_bf16(a0, b, acc[0][nf], 0, 0, 0);
            acc[1][nf] = __builtin_amdgcn_mfma_f32_16x16x32_bf16(a1, b, acc[1][nf], 0, 0, 0);
        }
    }

    #pragma unroll
    for (int mf = 0; mf < 2; mf++) {
        #pragma unroll
        for (int r = 0; r < 4; r++) {
            const int row = row0 + mf * 16 + (lane >> 4) * 4 + r;
            if (row >= Nn) continue;
            const int d = degi[row];
            #pragma unroll
            for (int nf = 0; nf < 8; nf++) {
                const int col = nf * 16 + lr;
                float o = acc[mf][nf][r];
                if (d == 0) {
                    // isolated node (rare): Sn row is 0; loop term must use Ew
                    o = 0.f;
                    for (int k = 0; k < HD; k++)
                        o = fmaf(bf2f(Hn[(size_t)row * HD + k]), Ew[(size_t)k * HD + col], o);
                }
                o = (o >= 0.f) ? o : o * SLOPE;
                if (STORE_BF16) ((u16*)Out)[(size_t)row * HD + col] = f2bf(o);
                else            ((float*)Out)[(size_t)row * HD + col] = o;
            }
        }
    }
}

// ---- gather + time embedding -> FP32 output [R, 192] -----------------------
__global__ __launch_bounds__(192)
void out_kernel(const float* __restrict__ h2, const int* __restrict__ ids,
                const int* __restrict__ tms,
                const float* __restrict__ tw, const float* __restrict__ tb,
                float* __restrict__ out, int R, int Nn)
{
    int r = blockIdx.x;
    int c = threadIdx.x;
    if (r >= R) return;
    float v;
    if (c < HD) {
        int id = ids[r];
        v = (id >= 0 && id < Nn) ? h2[(size_t)id * HD + c] : 0.0f;
    } else {
        int j = c - HD;
        v = cosf((float)tms[r] * tw[j] + tb[j]);
    }
    out[(size_t)r * (HD + TD) + c] = v;
}

extern "C" void kernel_launch(void* const* d_in, const int* in_sizes, int n_in,
                              void* d_out, int out_size, void* d_ws, size_t ws_size,
                              hipStream_t stream)
{
    const float* h   = (const float*)d_in[0];
    const float* rel = (const float*)d_in[1];
    const float* wn1 = (const float*)d_in[2];
    const float* lw1 = (const float*)d_in[3];
    const float* ew1 = (const float*)d_in[4];
    const float* wn2 = (const float*)d_in[5];
    const float* lw2 = (const float*)d_in[6];
    const float* ew2 = (const float*)d_in[7];
    const float* tw  = (const float*)d_in[8];
    const float* tb  = (const float*)d_in[9];
    const int* src = (const int*)d_in[10];
    const int* dst = (const int*)d_in[11];
    const int* ety = (const int*)d_in[12];
    const int* ids = (const int*)d_in[13];
    const int* tms = (const int*)d_in[14];

    const int Nn = in_sizes[0] / HD;
    const int E  = in_sizes[10];
    const int R  = in_sizes[13];
    const int NR2 = in_sizes[1] / HD;                     // 460
    const int NB = (Nn + 1023) / 1024;
    const size_t bfB = (size_t)Nn * HD * sizeof(u16);     // 12.8 MB

    // ws: degi | cursor | blocksum | rowstart | elist(u32) | hbf | h1bf | Sn | h2 | relbf | BT1 | BT2
    char* ws = (char*)d_ws;
    const size_t iN = ((size_t)Nn * sizeof(int) + 255) & ~(size_t)255;
    const size_t bN = ((size_t)NB * sizeof(int) + 255) & ~(size_t)255;
    int*  degi     = (int*)(ws);
    int*  cursor   = (int*)(ws + iN);
    int*  blocksum = (int*)(ws + 2 * iN);
    int*  rowstart = (int*)(ws + 2 * iN + bN);
    char* p        = ws + 2 * iN + bN + iN + 256;
    u32*  elist    = (u32*)p;                p += ((size_t)E * sizeof(u32) + 255) & ~(size_t)255;
    u16*  hbf      = (u16*)p;                p += bfB;
    u16*  h1bf     = (u16*)p;                p += bfB;
    u16*  Sn       = (u16*)p;                p += bfB;
    float* h2      = (float*)p;              p += (size_t)Nn * HD * sizeof(float);
    u16*  relbf    = (u16*)p;                p += ((size_t)NR2 * HD * sizeof(u16) + 255) & ~(size_t)255;
    u16*  BT1      = (u16*)p;                p += HD * 256 * sizeof(u16);
    u16*  BT2      = (u16*)p;

    hipMemsetAsync(ws, 0, 2 * iN, stream);   // degi + cursor

    const int eb = (E + 255) / 256;
    const int gb = (Nn + 127) / 128;
    const int n4 = Nn * HD / 4;
    const int r4 = NR2 * HD / 4;

    // CSR build
    deg_kernel<<<eb, 256, 0, stream>>>(dst, E, degi);
    scan1_kernel<<<NB, 256, 0, stream>>>(degi, blocksum, Nn);
    scan2_kernel<<<1, 64, 0, stream>>>(blocksum, NB, &rowstart[Nn]);
    scan3_kernel<<<NB, 1024, 0, stream>>>(degi, blocksum, rowstart, Nn);
    fill_kernel<<<eb, 256, 0, stream>>>(src, dst, ety, rowstart, cursor, elist, E);

    // conversions
    conv_kernel<<<(n4 + 255) / 256, 256, 0, stream>>>((const float4*)h, (ushort4*)hbf, n4);
    conv_kernel<<<(r4 + 255) / 256, 256, 0, stream>>>((const float4*)rel, (ushort4*)relbf, r4);
    bt_kernel<<<128, 256, 0, stream>>>(wn1, lw1, BT1);
    bt_kernel<<<128, 256, 0, stream>>>(wn2, lw2, BT2);

    // layer 1: h(bf16) -> h1(bf16)
    gagg_kernel<<<Nn, 64, 0, stream>>>((const u32*)hbf, (const u32*)relbf,
                                       elist, rowstart, (u32*)Sn, Nn);
    mfma_kernel<1><<<gb, 256, 0, stream>>>(Sn, hbf, BT1, degi, ew1, h1bf, Nn);

    // layer 2: h1(bf16) -> h2(fp32)
    gagg_kernel<<<Nn, 64, 0, stream>>>((const u32*)h1bf, (const u32*)relbf,
                                       elist, rowstart, (u32*)Sn, Nn);
    mfma_kernel<0><<<gb, 256, 0, stream>>>(Sn, h1bf, BT2, degi, ew2, h2, Nn);

    // output (fp32)
    out_kernel<<<R, 192, 0, stream>>>(h2, ids, tms, tw, tb, (float*)d_out, R, Nn);
}